// Round 9
// baseline (1760.696 us; speedup 1.0000x reference)
//
#include <hip/hip_runtime.h>
#include <hip/hip_bf16.h>

#define F 128
#define ET 7
#define NT 32    // nodes per block in fused kernel
#define BSH 9    // bin = 512 nodes
#define BW  (1 << BSH)

typedef __attribute__((ext_vector_type(8))) short short8;
typedef __attribute__((ext_vector_type(4))) float f32x4;
typedef __attribute__((ext_vector_type(4))) unsigned uint4v;

static __device__ __forceinline__ unsigned f2bf(float f) {
    unsigned u = __builtin_bit_cast(unsigned, f);
    unsigned r = u + 0x7fffu + ((u >> 16) & 1u);   // RTNE
    return r >> 16;
}
static __device__ __forceinline__ float bf2f(unsigned short h) {
    unsigned u = ((unsigned)h) << 16;
    return __builtin_bit_cast(float, u);
}
static __device__ __forceinline__ float lo16(unsigned v) {
    return __builtin_bit_cast(float, v << 16);
}
static __device__ __forceinline__ float hi16(unsigned v) {
    return __builtin_bit_cast(float, v & 0xffff0000u);
}

// ---------------- W pre-pack into MFMA B-fragment order (verified r1) --------
__global__ __launch_bounds__(256) void prep_wfrag(const float* __restrict__ W,
                                                  unsigned short* __restrict__ Wfrag) {
    int tid = blockIdx.x * blockDim.x + threadIdx.x;
    if (tid >= ET * 2048) return;
    int i   = tid >> 11;
    int rem = tid & 2047;
    int c   = rem >> 8;
    int kk  = (rem >> 6) & 3;
    int l   = rem & 63;
    const float* Wi = W + (size_t)i * F * F;
    unsigned short* dst = Wfrag + (size_t)tid * 8;
    int o  = c * 16 + (l & 15);
    int kb = kk * 32 + 4 * (l >> 4);
#pragma unroll
    for (int e = 0; e < 8; ++e) {
        int k = kb + (e & 3) + 16 * (e >> 2);
        dst[e] = (unsigned short)f2bf(Wi[k * F + o]);
    }
}

// ---------------- x -> bf16-packed, batch-interleaved: xb[n][b][64] dwords ---
__global__ __launch_bounds__(256) void xb_convert(const float* __restrict__ x,
                                                  unsigned* __restrict__ xb,
                                                  int N, long n_pairs) {
    long stride = (long)gridDim.x * blockDim.x;
    for (long t = (long)blockIdx.x * blockDim.x + threadIdx.x; t < n_pairs; t += stride) {
        long row = t >> 6;          // source row = b*N + n
        int  c   = (int)(t & 63);
        int  b   = row >= N;
        long n   = row - (long)b * N;
        float2 v = ((const float2*)x)[t];
        xb[(n << 7) + b * 64 + c] = f2bf(v.x) | (f2bf(v.y) << 16);
    }
}

// ================= NEW bucketed CSR build ====================================
// bins of 512 nodes per type; nbins = ceil(N/512); nbt = 7*nbins.

__global__ __launch_bounds__(256) void hist_bins(const int* __restrict__ startn,
                                                 int* __restrict__ bincnt,
                                                 int N, int E, int nbins) {
    int e = blockIdx.x * 256 + threadIdx.x;
    if (e >= E) return;
    int i  = blockIdx.y;
    int sn = startn[(size_t)i * E + e];
    atomicAdd(&bincnt[i * nbins + (sn >> BSH)], 1);
}

// single block: exclusive scan of nbt bin counts -> bases & cursor; sentinels.
__global__ __launch_bounds__(256) void scan_bins(const int* __restrict__ bincnt,
                                                 int* __restrict__ bases,
                                                 int* __restrict__ cursor,
                                                 int nbt, int totE,
                                                 int* __restrict__ offsets, int CN) {
    __shared__ int sh[256];
    int carry = 0;
    for (int base = 0; base < nbt; base += 256) {
        int idx = base + threadIdx.x;
        int v = idx < nbt ? bincnt[idx] : 0;
        __syncthreads();
        sh[threadIdx.x] = v;
        __syncthreads();
        for (int o = 1; o < 256; o <<= 1) {
            int t = (int)threadIdx.x >= o ? sh[threadIdx.x - o] : 0;
            __syncthreads();
            sh[threadIdx.x] += t;
            __syncthreads();
        }
        int incl = sh[threadIdx.x];
        int total = sh[255];
        if (idx < nbt) {
            int excl = incl - v + carry;
            bases[idx]  = excl;
            cursor[idx] = excl;
        }
        carry += total;
    }
    if (threadIdx.x == 0) {
        bases[nbt]   = totE;
        offsets[CN]  = totE;
    }
}

// append edges to their bin: sequential write frontier per bin (L2-hot).
// tmp.x = en | (sn & 511) << 17   (needs N < 2^17)
__global__ __launch_bounds__(256) void bucket_scatter(const int* __restrict__ startn,
                                                      const int* __restrict__ endn,
                                                      const float* __restrict__ adj,
                                                      int* __restrict__ cursor,
                                                      int2* __restrict__ tmp,
                                                      int N, int E, int nbins) {
    int e = blockIdx.x * 256 + threadIdx.x;
    if (e >= E) return;
    int i  = blockIdx.y;
    size_t g = (size_t)i * E + e;
    int sn = startn[g];
    int pos = atomicAdd(&cursor[i * nbins + (sn >> BSH)], 1);
    tmp[pos] = make_int2(endn[g] | ((sn & (BW - 1)) << 17),
                         __builtin_bit_cast(int, adj[g]));
}

// per-bin counting sort -> exact CSR payload + per-node offsets.
__global__ __launch_bounds__(256) void bin_sort(const int2* __restrict__ tmp,
                                                const int* __restrict__ bases,
                                                int* __restrict__ offsets,
                                                int2* __restrict__ payload,
                                                int N, int nbins) {
    __shared__ int cs[BW];     // counts, then cursors
    __shared__ int ex[BW];     // exclusive offsets
    __shared__ int sh[256];
    int i   = blockIdx.y;
    int b   = blockIdx.x;
    int bid = i * nbins + b;
    int base = bases[bid];
    int endp = bases[bid + 1];
    int b0   = b << BSH;
    int span = N - b0; if (span > BW) span = BW;
    int t = threadIdx.x;

    cs[t] = 0; cs[t + 256] = 0;
    __syncthreads();
    for (int k = base + t; k < endp; k += 256)
        atomicAdd(&cs[(tmp[k].x >> 17) & (BW - 1)], 1);
    __syncthreads();
    // pair scan: thread t owns entries 2t, 2t+1
    int c0 = cs[2 * t], c1 = cs[2 * t + 1];
    int ps = c0 + c1;
    sh[t] = ps;
    __syncthreads();
    for (int o = 1; o < 256; o <<= 1) {
        int v = t >= o ? sh[t - o] : 0;
        __syncthreads();
        sh[t] += v;
        __syncthreads();
    }
    int ep = sh[t] - ps;
    ex[2 * t] = ep;
    ex[2 * t + 1] = ep + c0;
    __syncthreads();
    // per-node CSR offsets (degree-0 nodes handled naturally)
    if (t < span)       offsets[(size_t)i * N + b0 + t]       = base + ex[t];
    if (t + 256 < span) offsets[(size_t)i * N + b0 + t + 256] = base + ex[t + 256];
    // reset cursors (same-thread entries)
    cs[2 * t] = ex[2 * t];
    cs[2 * t + 1] = ex[2 * t + 1];
    __syncthreads();
    // scatter to sorted positions (bin region is L2-hot)
    for (int k = base + t; k < endp; k += 256) {
        int2 p = tmp[k];
        int nib = (p.x >> 17) & (BW - 1);
        int pos = base + atomicAdd(&cs[nib], 1);
        payload[pos] = make_int2((p.x & 0x1FFFF) | ((nib & (NT - 1)) << 20), p.y);
    }
}

// ================= OLD CSR build (fallback tier, round-2 verified) ===========
__global__ __launch_bounds__(256) void hist_kernel(const int* __restrict__ startn,
                                                   int* __restrict__ counts,
                                                   int N, int E, int totE) {
    int tid = blockIdx.x * 256 + threadIdx.x;
    if (tid >= totE) return;
    int i = tid / E;
    atomicAdd(&counts[i * N + startn[tid]], 1);
}

__global__ __launch_bounds__(256) void block_sum(const int* __restrict__ counts,
                                                 int* __restrict__ partials, int CN) {
    int gid = blockIdx.x * 256 + threadIdx.x;
    int v = gid < CN ? counts[gid] : 0;
#pragma unroll
    for (int off = 1; off < 64; off <<= 1) v += __shfl_xor(v, off);
    __shared__ int sh[4];
    if ((threadIdx.x & 63) == 0) sh[threadIdx.x >> 6] = v;
    __syncthreads();
    if (threadIdx.x == 0) partials[blockIdx.x] = sh[0] + sh[1] + sh[2] + sh[3];
}

__global__ __launch_bounds__(256) void scan_partials(int* __restrict__ partials, int nblk) {
    __shared__ int sh[256];
    int carry = 0;
    for (int base = 0; base < nblk; base += 256) {
        int idx = base + threadIdx.x;
        int v = idx < nblk ? partials[idx] : 0;
        __syncthreads();
        sh[threadIdx.x] = v;
        __syncthreads();
        for (int o = 1; o < 256; o <<= 1) {
            int t = (int)threadIdx.x >= o ? sh[threadIdx.x - o] : 0;
            __syncthreads();
            sh[threadIdx.x] += t;
            __syncthreads();
        }
        int incl = sh[threadIdx.x];
        int total = sh[255];
        if (idx < nblk) partials[idx] = incl - v + carry;
        carry += total;
    }
}

__global__ __launch_bounds__(256) void scan_blocks(const int* __restrict__ counts,
                                                   const int* __restrict__ partials,
                                                   int* __restrict__ offsets,
                                                   int* __restrict__ cursor,
                                                   int CN, int totE) {
    __shared__ int sh[256];
    int gid = blockIdx.x * 256 + threadIdx.x;
    int v = gid < CN ? counts[gid] : 0;
    sh[threadIdx.x] = v;
    __syncthreads();
    for (int o = 1; o < 256; o <<= 1) {
        int t = (int)threadIdx.x >= o ? sh[threadIdx.x - o] : 0;
        __syncthreads();
        sh[threadIdx.x] += t;
        __syncthreads();
    }
    int excl = sh[threadIdx.x] - v + partials[blockIdx.x];
    if (gid < CN) { offsets[gid] = excl; cursor[gid] = excl; }
    if (gid == CN - 1) offsets[CN] = totE;
}

__global__ __launch_bounds__(256) void fill_csr(const int* __restrict__ startn,
                                                const int* __restrict__ endn,
                                                const float* __restrict__ adj,
                                                int* __restrict__ cursor,
                                                int2* __restrict__ payload,
                                                int N, int E, int totE) {
    int tid = blockIdx.x * 256 + threadIdx.x;
    if (tid >= totE) return;
    int i = tid / E;
    int sn = startn[tid];
    int pos = atomicAdd(&cursor[i * N + sn], 1);
    int px = endn[tid] | ((sn & (NT - 1)) << 20);
    payload[pos] = make_int2(px, __builtin_bit_cast(int, adj[tid]));
}

// ---------------- fused aggregate-then-project (round-8 verified, UNCHANGED) --
__global__ __launch_bounds__(512, 4) void fused_agg_gemm(
        const unsigned* __restrict__ xb,          // [N][2][64] dwords (bf16x2)
        const unsigned short* __restrict__ Wfrag, // [7][2048][8]
        const float* __restrict__ bias,           // [7][128]
        const int* __restrict__ offsets,          // [7N+1]
        const int2* __restrict__ payload,         // [7E]
        float* __restrict__ out, int N) {
    __shared__ unsigned ylds[64 * 64];            // 64 rows x 64 dwords, swizzled
    __shared__ float sadjl[ET][NT];
    __shared__ int offs[ET][NT + 1];

    int tid  = threadIdx.x;
    int wave = tid >> 6;
    int lane = tid & 63;
    int hl   = lane & 31;
    int hb   = lane >> 5;          // batch this lane covers
    int lr   = lane & 15;
    int lg   = lane >> 4;
    int rt   = wave & 3;           // row-tile for MFMA
    int ct4  = (wave >> 2) * 4;    // col-tile base for MFMA
    int n0   = blockIdx.x * NT;

    if (tid < ET * (NT + 1)) {
        int i = tid / (NT + 1);
        int j = tid - i * (NT + 1);
        int n = n0 + j;
        ((int*)offs)[tid] = offsets[i * N + (n < N ? n : N)];
    }

    f32x4 acc[4];
#pragma unroll
    for (int c = 0; c < 4; ++c) acc[c] = (f32x4){0.f, 0.f, 0.f, 0.f};

    __syncthreads();

    const unsigned laneoff = (hb << 6) + (hl << 1);
    const int colw = hl << 1;

    for (int i = 0; i < ET; ++i) {
        int base = offs[i][0];
        int tot  = offs[i][NT] - base;
        int tgt_s = base + (int)(((long)tot * wave) >> 3);
        int tgt_e = base + (int)(((long)tot * (wave + 1)) >> 3);
        int oj = (lane <= NT) ? offs[i][lane] : 0x7fffffff;
        unsigned long long ms = __ballot(oj >= tgt_s);
        unsigned long long me = __ballot(oj >= tgt_e);
        int js = __ffsll(ms) - 1;
        int je = (wave == 7) ? NT : (__ffsll(me) - 1);
        int kb = offs[i][js];
        int ke = offs[i][je];

        int cur = -1;
        float a0 = 0.f, a1 = 0.f, a2 = 0.f, a3 = 0.f, asum = 0.f;
        for (int k = kb; k < ke; k += 8) {
            int2 p[8];
            uint2 v[8];
#pragma unroll
            for (int j = 0; j < 8; ++j) {
                int idx = (k + j < ke) ? k + j : ke - 1;
                p[j] = payload[idx];
            }
#pragma unroll
            for (int j = 0; j < 8; ++j) {
                v[j] = *(const uint2*)(xb + (((size_t)(p[j].x & 0xFFFFF)) << 7) + laneoff);
            }
#pragma unroll
            for (int j = 0; j < 8; ++j) {
                bool ok = (k + j) < ke;
                float w = ok ? __builtin_bit_cast(float, p[j].y) : 0.f;
                int nl = (p[j].x >> 20) & (NT - 1);
                if (ok && nl != cur) {
                    if (cur >= 0) {
                        unsigned pk0 = f2bf(a0) | (f2bf(a1) << 16);
                        unsigned pk1 = f2bf(a2) | (f2bf(a3) << 16);
                        int r = hb * NT + cur;
                        *(uint2*)&ylds[(r * 64 + colw) ^ ((r & 7) << 2)] = make_uint2(pk0, pk1);
                        if (lane == 0) sadjl[i][cur] = asum;
                    }
                    cur = nl;
                    a0 = a1 = a2 = a3 = asum = 0.f;
                }
                asum += w;
                a0 += w * lo16(v[j].x); a1 += w * hi16(v[j].x);
                a2 += w * lo16(v[j].y); a3 += w * hi16(v[j].y);
            }
        }
        if (cur >= 0) {
            unsigned pk0 = f2bf(a0) | (f2bf(a1) << 16);
            unsigned pk1 = f2bf(a2) | (f2bf(a3) << 16);
            int r = hb * NT + cur;
            *(uint2*)&ylds[(r * 64 + colw) ^ ((r & 7) << 2)] = make_uint2(pk0, pk1);
            if (lane == 0) sadjl[i][cur] = asum;
        }
        for (int j = js; j < je; ++j) {
            if (offs[i][j + 1] == offs[i][j]) {
                int r = hb * NT + j;
                *(uint2*)&ylds[(r * 64 + colw) ^ ((r & 7) << 2)] = make_uint2(0u, 0u);
                if (lane == 0) sadjl[i][j] = 0.f;
            }
        }
        __syncthreads();

        int row = rt * 16 + lr;
        int s = (row & 7) << 2;
#pragma unroll
        for (int kk = 0; kk < 4; ++kk) {
            int d0 = (row * 64 + kk * 16 + lg * 2) ^ s;
            int d1 = (row * 64 + kk * 16 + lg * 2 + 8) ^ s;
            uint2 c0 = *(const uint2*)&ylds[d0];
            uint2 c1 = *(const uint2*)&ylds[d1];
            uint4v av = {c0.x, c0.y, c1.x, c1.y};
            short8 afrag = __builtin_bit_cast(short8, av);
            const unsigned short* wbp = Wfrag + ((size_t)i * 2048 + (size_t)kk * 64 + lane) * 8;
#pragma unroll
            for (int c = 0; c < 4; ++c) {
                short8 bfrag = *(const short8*)(wbp + (size_t)(ct4 + c) * 2048);
                acc[c] = __builtin_amdgcn_mfma_f32_16x16x32_bf16(afrag, bfrag, acc[c], 0, 0, 0);
            }
        }
        __syncthreads();
    }

#pragma unroll
    for (int c = 0; c < 4; ++c) {
        int col = (ct4 + c) * 16 + lr;
        float bv[ET];
#pragma unroll
        for (int i = 0; i < ET; ++i) bv[i] = bias[i * F + col];
#pragma unroll
        for (int j = 0; j < 4; ++j) {
            int row = rt * 16 + lg * 4 + j;
            int nl = row & (NT - 1);
            int b  = row >> 5;
            int n  = n0 + nl;
            float vv = acc[c][j];
#pragma unroll
            for (int i = 0; i < ET; ++i) vv += sadjl[i][nl] * bv[i];
            if (n < N) out[((size_t)(b * N + n)) * F + col] = vv;
        }
    }
}

// ---------------- fallbacks --------------------------------------------------
__global__ __launch_bounds__(256) void gemm_h(const float* __restrict__ x,
                                              const unsigned short* __restrict__ Wfrag,
                                              const float* __restrict__ bias,
                                              unsigned short* __restrict__ hb,
                                              int M) {
    int wave = threadIdx.x >> 6;
    int lane = threadIdx.x & 63;
    int row_base = blockIdx.x * 128 + wave * 32;
    int lr = lane & 15;
    int lg = lane >> 4;
    f32x4 acc[2][8];
#pragma unroll
    for (int t = 0; t < 2; ++t)
#pragma unroll
        for (int c = 0; c < 8; ++c)
            acc[t][c] = (f32x4){0.f, 0.f, 0.f, 0.f};
#pragma unroll
    for (int kk = 0; kk < 4; ++kk) {
        int k0 = kk * 32 + 4 * lg;
        short8 afrag[2];
#pragma unroll
        for (int t = 0; t < 2; ++t) {
            int r = row_base + t * 16 + lr;
            r = r < M ? r : M - 1;
            float4 v0 = *(const float4*)(x + (size_t)r * F + k0);
            float4 v1 = *(const float4*)(x + (size_t)r * F + k0 + 16);
            short8 a;
            a[0] = (short)f2bf(v0.x); a[1] = (short)f2bf(v0.y);
            a[2] = (short)f2bf(v0.z); a[3] = (short)f2bf(v0.w);
            a[4] = (short)f2bf(v1.x); a[5] = (short)f2bf(v1.y);
            a[6] = (short)f2bf(v1.z); a[7] = (short)f2bf(v1.w);
            afrag[t] = a;
        }
#pragma unroll
        for (int c = 0; c < 8; ++c) {
            short8 bfrag = *(const short8*)(Wfrag + (size_t)((c * 4 + kk) * 64 + lane) * 8);
            acc[0][c] = __builtin_amdgcn_mfma_f32_16x16x32_bf16(afrag[0], bfrag, acc[0][c], 0, 0, 0);
            acc[1][c] = __builtin_amdgcn_mfma_f32_16x16x32_bf16(afrag[1], bfrag, acc[1][c], 0, 0, 0);
        }
    }
#pragma unroll
    for (int c = 0; c < 8; ++c) {
        int o = c * 16 + lr;
        float bvv = bias[o];
#pragma unroll
        for (int t = 0; t < 2; ++t)
#pragma unroll
            for (int j = 0; j < 4; ++j) {
                int r = row_base + t * 16 + lg * 4 + j;
                if (r < M) hb[(size_t)r * F + o] = (unsigned short)f2bf(acc[t][c][j] + bvv);
            }
    }
}

__global__ __launch_bounds__(256) void edge_scatter(const unsigned short* __restrict__ hb,
                                                    const float* __restrict__ adj,
                                                    const int* __restrict__ endn,
                                                    const int* __restrict__ startn,
                                                    float* __restrict__ out,
                                                    int N, int E) {
    int e = blockIdx.x;
    if (e >= E) return;
    int b = threadIdx.x >> 7;
    int f = threadIdx.x & 127;
    float a = adj[e];
    int en = endn[e];
    int sn = startn[e];
    float v = a * bf2f(hb[((size_t)(b * N + en)) * F + f]);
    unsafeAtomicAdd(&out[((size_t)(b * N + sn)) * F + f], v);
}

__global__ __launch_bounds__(256) void edge_fused_slow(const float* __restrict__ x,
                                                       const float* __restrict__ W,
                                                       const float* __restrict__ bias,
                                                       const float* __restrict__ adj,
                                                       const int* __restrict__ endn,
                                                       const int* __restrict__ startn,
                                                       float* __restrict__ out,
                                                       int N, int E) {
    __shared__ float xrow[2][F];
    int e = blockIdx.x;
    if (e >= E) return;
    int b = threadIdx.x >> 7;
    int f = threadIdx.x & 127;
    int en = endn[e], sn = startn[e];
    xrow[b][f] = x[((size_t)(b * N + en)) * F + f];
    __syncthreads();
    float acc = bias[f];
#pragma unroll 8
    for (int k = 0; k < F; ++k) acc += xrow[b][k] * W[k * F + f];
    unsafeAtomicAdd(&out[((size_t)(b * N + sn)) * F + f], adj[e] * acc);
}

// ---------------- launch -----------------------------------------------------
extern "C" void kernel_launch(void* const* d_in, const int* in_sizes, int n_in,
                              void* d_out, int out_size, void* d_ws, size_t ws_size,
                              hipStream_t stream) {
    const float* x      = (const float*)d_in[0];
    const float* W      = (const float*)d_in[1];
    const float* bias   = (const float*)d_in[2];
    const float* adj    = (const float*)d_in[3];
    const int*   endn   = (const int*)d_in[4];
    const int*   startn = (const int*)d_in[5];

    const int B = 2;
    const int N = in_sizes[0] / (B * F);  // 100000
    const int E = in_sizes[3] / ET;       // 400000
    const int M = B * N;                  // 200000
    const int totE = ET * E;              // 2.8M
    const int CN = ET * N;                // 700000
    const int nblk = (CN + 255) / 256;
    const int nbins = (N + BW - 1) >> BSH;
    const int nbt = ET * nbins;
    float* out = (float*)d_out;

    // --- bucket-path ws layout ---
    size_t off = 0;
    auto take = [&](size_t bytes) { size_t o = off; off = (off + bytes + 255) & ~(size_t)255; return o; };
    size_t o_wfrag   = take((size_t)ET * F * F * 2);
    size_t o_bincnt  = take((size_t)nbt * 4);
    size_t o_bases   = take((size_t)(nbt + 1) * 4);
    size_t o_bcur    = take((size_t)nbt * 4);
    size_t o_offsets = take((size_t)(CN + 1) * 4);
    size_t o_tmp     = take((size_t)totE * 8);
    size_t o_payload = take((size_t)totE * 8);
    size_t o_xb      = take((size_t)M * F * 2);
    size_t need_bucket = off;

    // --- old-path ws layout ---
    off = 0;
    size_t q_wfrag    = take((size_t)ET * F * F * 2);
    size_t q_counts   = take((size_t)CN * 4);
    size_t q_offsets  = take((size_t)(CN + 1) * 4);
    size_t q_cursor   = take((size_t)CN * 4);
    size_t q_partials = take((size_t)nblk * 4);
    size_t q_payload  = take((size_t)totE * 8);
    size_t q_xb       = take((size_t)M * F * 2);
    size_t need_old_csr = off;
    size_t need_r1 = 256 * 1024 + (size_t)M * F * 2;

    char* ws = (char*)d_ws;

    if (ws_size >= need_bucket && N < (1 << 17)) {
        unsigned short* Wfrag = (unsigned short*)(ws + o_wfrag);
        int*  bincnt  = (int*)(ws + o_bincnt);
        int*  bases   = (int*)(ws + o_bases);
        int*  bcur    = (int*)(ws + o_bcur);
        int*  offsets = (int*)(ws + o_offsets);
        int2* tmp     = (int2*)(ws + o_tmp);
        int2* payload = (int2*)(ws + o_payload);
        unsigned* xbuf = (unsigned*)(ws + o_xb);

        hipMemsetAsync(bincnt, 0, (size_t)nbt * 4, stream);
        prep_wfrag<<<(ET * 2048 + 255) / 256, 256, 0, stream>>>(W, Wfrag);
        xb_convert<<<2048, 256, 0, stream>>>(x, xbuf, N, (long)M * (F / 2));
        dim3 eg((E + 255) / 256, ET);
        hist_bins<<<eg, 256, 0, stream>>>(startn, bincnt, N, E, nbins);
        scan_bins<<<1, 256, 0, stream>>>(bincnt, bases, bcur, nbt, totE, offsets, CN);
        bucket_scatter<<<eg, 256, 0, stream>>>(startn, endn, adj, bcur, tmp, N, E, nbins);
        dim3 bg(nbins, ET);
        bin_sort<<<bg, 256, 0, stream>>>(tmp, bases, offsets, payload, N, nbins);

        int fgrid = (N + NT - 1) / NT;
        fused_agg_gemm<<<fgrid, 512, 0, stream>>>(xbuf, Wfrag, bias, offsets, payload, out, N);
    } else if (ws_size >= need_old_csr) {
        unsigned short* Wfrag = (unsigned short*)(ws + q_wfrag);
        int*  counts   = (int*)(ws + q_counts);
        int*  offsets  = (int*)(ws + q_offsets);
        int*  cursor   = (int*)(ws + q_cursor);
        int*  partials = (int*)(ws + q_partials);
        int2* payload  = (int2*)(ws + q_payload);
        unsigned* xbuf = (unsigned*)(ws + q_xb);

        hipMemsetAsync(counts, 0, (size_t)CN * 4, stream);
        prep_wfrag<<<(ET * 2048 + 255) / 256, 256, 0, stream>>>(W, Wfrag);
        xb_convert<<<2048, 256, 0, stream>>>(x, xbuf, N, (long)M * (F / 2));
        hist_kernel<<<(totE + 255) / 256, 256, 0, stream>>>(startn, counts, N, E, totE);
        block_sum<<<nblk, 256, 0, stream>>>(counts, partials, CN);
        scan_partials<<<1, 256, 0, stream>>>(partials, nblk);
        scan_blocks<<<nblk, 256, 0, stream>>>(counts, partials, offsets, cursor, CN, totE);
        fill_csr<<<(totE + 255) / 256, 256, 0, stream>>>(startn, endn, adj, cursor, payload, N, E, totE);

        int fgrid = (N + NT - 1) / NT;
        fused_agg_gemm<<<fgrid, 512, 0, stream>>>(xbuf, Wfrag, bias, offsets, payload, out, N);
    } else if (ws_size >= need_r1) {
        hipMemsetAsync(out, 0, (size_t)out_size * sizeof(float), stream);
        unsigned short* Wfrag = (unsigned short*)d_ws;
        unsigned short* hbuf  = (unsigned short*)((char*)d_ws + 256 * 1024);
        prep_wfrag<<<(ET * 2048 + 255) / 256, 256, 0, stream>>>(W, Wfrag);
        int ggrid = (M + 127) / 128;
        for (int i = 0; i < ET; ++i) {
            gemm_h<<<ggrid, 256, 0, stream>>>(x, Wfrag + (size_t)i * F * F, bias + i * F, hbuf, M);
            edge_scatter<<<E, 256, 0, stream>>>(hbuf, adj + (size_t)i * E, endn + (size_t)i * E,
                                                startn + (size_t)i * E, out, N, E);
        }
    } else {
        hipMemsetAsync(out, 0, (size_t)out_size * sizeof(float), stream);
        for (int i = 0; i < ET; ++i) {
            edge_fused_slow<<<E, 256, 0, stream>>>(x, W + (size_t)i * F * F, bias + i * F,
                                                   adj + (size_t)i * E, endn + (size_t)i * E,
                                                   startn + (size_t)i * E, out, N, E);
        }
    }
}

// Round 10
// 500.372 us; speedup vs baseline: 3.5188x; 3.5188x over previous
//
#include <hip/hip_runtime.h>
#include <hip/hip_bf16.h>

#define F 128
#define ET 7
#define NT 32    // nodes per block in fused kernel
#define BSH 9    // bin = 512 nodes
#define BW  (1 << BSH)
#define CHUNK 8192

typedef __attribute__((ext_vector_type(8))) short short8;
typedef __attribute__((ext_vector_type(4))) float f32x4;
typedef __attribute__((ext_vector_type(4))) unsigned uint4v;

static __device__ __forceinline__ unsigned f2bf(float f) {
    unsigned u = __builtin_bit_cast(unsigned, f);
    unsigned r = u + 0x7fffu + ((u >> 16) & 1u);   // RTNE
    return r >> 16;
}
static __device__ __forceinline__ float bf2f(unsigned short h) {
    unsigned u = ((unsigned)h) << 16;
    return __builtin_bit_cast(float, u);
}
static __device__ __forceinline__ float lo16(unsigned v) {
    return __builtin_bit_cast(float, v << 16);
}
static __device__ __forceinline__ float hi16(unsigned v) {
    return __builtin_bit_cast(float, v & 0xffff0000u);
}

// ---------------- W pre-pack into MFMA B-fragment order (verified r1) --------
__global__ __launch_bounds__(256) void prep_wfrag(const float* __restrict__ W,
                                                  unsigned short* __restrict__ Wfrag) {
    int tid = blockIdx.x * blockDim.x + threadIdx.x;
    if (tid >= ET * 2048) return;
    int i   = tid >> 11;
    int rem = tid & 2047;
    int c   = rem >> 8;
    int kk  = (rem >> 6) & 3;
    int l   = rem & 63;
    const float* Wi = W + (size_t)i * F * F;
    unsigned short* dst = Wfrag + (size_t)tid * 8;
    int o  = c * 16 + (l & 15);
    int kb = kk * 32 + 4 * (l >> 4);
#pragma unroll
    for (int e = 0; e < 8; ++e) {
        int k = kb + (e & 3) + 16 * (e >> 2);
        dst[e] = (unsigned short)f2bf(Wi[k * F + o]);
    }
}

// ---------------- x -> bf16-packed, batch-interleaved: xb[n][b][64] dwords ---
__global__ __launch_bounds__(256) void xb_convert(const float* __restrict__ x,
                                                  unsigned* __restrict__ xb,
                                                  int N, long n_pairs) {
    long stride = (long)gridDim.x * blockDim.x;
    for (long t = (long)blockIdx.x * blockDim.x + threadIdx.x; t < n_pairs; t += stride) {
        long row = t >> 6;          // source row = b*N + n
        int  c   = (int)(t & 63);
        int  b   = row >= N;
        long n   = row - (long)b * N;
        float2 v = ((const float2*)x)[t];
        xb[(n << 7) + b * 64 + c] = f2bf(v.x) | (f2bf(v.y) << 16);
    }
}

// ================= bucketed CSR build (v2: LDS-hist partition pass) ==========
// bins of 512 nodes per type; nbins = ceil(N/512); nbt = 7*nbins.

// per-block LDS histogram -> one global add per (block,bin): no contention.
__global__ __launch_bounds__(256) void hist_bins2(const int* __restrict__ startn,
                                                  int* __restrict__ bincnt,
                                                  int E, int nbins) {
    __shared__ int lcnt[BW];
    int i  = blockIdx.y;
    int e0 = blockIdx.x * CHUNK;
    int e1 = e0 + CHUNK < E ? e0 + CHUNK : E;
    int t  = threadIdx.x;
    for (int b = t; b < nbins; b += 256) lcnt[b] = 0;
    __syncthreads();
    for (int e = e0 + t; e < e1; e += 256)
        atomicAdd(&lcnt[startn[(size_t)i * E + e] >> BSH], 1);
    __syncthreads();
    for (int b = t; b < nbins; b += 256)
        if (lcnt[b]) atomicAdd(&bincnt[i * nbins + b], lcnt[b]);
}

// single block: exclusive scan of nbt bin counts -> bases & cursor; sentinels.
__global__ __launch_bounds__(256) void scan_bins(const int* __restrict__ bincnt,
                                                 int* __restrict__ bases,
                                                 int* __restrict__ cursor,
                                                 int nbt, int totE,
                                                 int* __restrict__ offsets, int CN) {
    __shared__ int sh[256];
    int carry = 0;
    for (int base = 0; base < nbt; base += 256) {
        int idx = base + threadIdx.x;
        int v = idx < nbt ? bincnt[idx] : 0;
        __syncthreads();
        sh[threadIdx.x] = v;
        __syncthreads();
        for (int o = 1; o < 256; o <<= 1) {
            int t = (int)threadIdx.x >= o ? sh[threadIdx.x - o] : 0;
            __syncthreads();
            sh[threadIdx.x] += t;
            __syncthreads();
        }
        int incl = sh[threadIdx.x];
        int total = sh[255];
        if (idx < nbt) {
            int excl = incl - v + carry;
            bases[idx]  = excl;
            cursor[idx] = excl;
        }
        carry += total;
    }
    if (threadIdx.x == 0) {
        bases[nbt]   = totE;
        offsets[CN]  = totE;
    }
}

// partition pass: per-block LDS hist -> ONE returning atomic per (block,bin)
// reserves a range -> edges written sequentially into the reservation.
// tmp.x = en | (sn & 511) << 17   (needs N < 2^17, en < 2^17)
__global__ __launch_bounds__(256) void bucket_scatter2(const int* __restrict__ startn,
                                                       const int* __restrict__ endn,
                                                       const float* __restrict__ adj,
                                                       int* __restrict__ cursor,
                                                       int2* __restrict__ tmp,
                                                       int E, int nbins) {
    __shared__ int lcnt[BW];
    __shared__ int lbase[BW];
    int i  = blockIdx.y;
    int e0 = blockIdx.x * CHUNK;
    int e1 = e0 + CHUNK < E ? e0 + CHUNK : E;
    int t  = threadIdx.x;
    for (int b = t; b < nbins; b += 256) lcnt[b] = 0;
    __syncthreads();
    for (int e = e0 + t; e < e1; e += 256)
        atomicAdd(&lcnt[startn[(size_t)i * E + e] >> BSH], 1);
    __syncthreads();
    for (int b = t; b < nbins; b += 256) {
        int c = lcnt[b];
        lbase[b] = c ? atomicAdd(&cursor[i * nbins + b], c) : 0;
        lcnt[b] = 0;
    }
    __syncthreads();
    for (int e = e0 + t; e < e1; e += 256) {
        size_t g = (size_t)i * E + e;
        int sn = startn[g];
        int b  = sn >> BSH;
        int pos = lbase[b] + atomicAdd(&lcnt[b], 1);
        tmp[pos] = make_int2(endn[g] | ((sn & (BW - 1)) << 17),
                             __builtin_bit_cast(int, adj[g]));
    }
}

// per-bin counting sort -> exact CSR payload + per-node offsets.
__global__ __launch_bounds__(256) void bin_sort(const int2* __restrict__ tmp,
                                                const int* __restrict__ bases,
                                                int* __restrict__ offsets,
                                                int2* __restrict__ payload,
                                                int N, int nbins) {
    __shared__ int cs[BW];     // counts, then cursors
    __shared__ int ex[BW];     // exclusive offsets
    __shared__ int sh[256];
    int i   = blockIdx.y;
    int b   = blockIdx.x;
    int bid = i * nbins + b;
    int base = bases[bid];
    int endp = bases[bid + 1];
    int b0   = b << BSH;
    int span = N - b0; if (span > BW) span = BW;
    int t = threadIdx.x;

    cs[t] = 0; cs[t + 256] = 0;
    __syncthreads();
    for (int k = base + t; k < endp; k += 256)
        atomicAdd(&cs[(tmp[k].x >> 17) & (BW - 1)], 1);
    __syncthreads();
    int c0 = cs[2 * t], c1 = cs[2 * t + 1];
    int ps = c0 + c1;
    sh[t] = ps;
    __syncthreads();
    for (int o = 1; o < 256; o <<= 1) {
        int v = t >= o ? sh[t - o] : 0;
        __syncthreads();
        sh[t] += v;
        __syncthreads();
    }
    int ep = sh[t] - ps;
    ex[2 * t] = ep;
    ex[2 * t + 1] = ep + c0;
    __syncthreads();
    if (t < span)       offsets[(size_t)i * N + b0 + t]       = base + ex[t];
    if (t + 256 < span) offsets[(size_t)i * N + b0 + t + 256] = base + ex[t + 256];
    cs[2 * t] = ex[2 * t];
    cs[2 * t + 1] = ex[2 * t + 1];
    __syncthreads();
    for (int k = base + t; k < endp; k += 256) {
        int2 p = tmp[k];
        int nib = (p.x >> 17) & (BW - 1);
        int pos = base + atomicAdd(&cs[nib], 1);
        payload[pos] = make_int2((p.x & 0x1FFFF) | ((nib & (NT - 1)) << 20), p.y);
    }
}

// ================= OLD CSR build (fallback tier, round-2 verified) ===========
__global__ __launch_bounds__(256) void hist_kernel(const int* __restrict__ startn,
                                                   int* __restrict__ counts,
                                                   int N, int E, int totE) {
    int tid = blockIdx.x * 256 + threadIdx.x;
    if (tid >= totE) return;
    int i = tid / E;
    atomicAdd(&counts[i * N + startn[tid]], 1);
}

__global__ __launch_bounds__(256) void block_sum(const int* __restrict__ counts,
                                                 int* __restrict__ partials, int CN) {
    int gid = blockIdx.x * 256 + threadIdx.x;
    int v = gid < CN ? counts[gid] : 0;
#pragma unroll
    for (int off = 1; off < 64; off <<= 1) v += __shfl_xor(v, off);
    __shared__ int sh[4];
    if ((threadIdx.x & 63) == 0) sh[threadIdx.x >> 6] = v;
    __syncthreads();
    if (threadIdx.x == 0) partials[blockIdx.x] = sh[0] + sh[1] + sh[2] + sh[3];
}

__global__ __launch_bounds__(256) void scan_partials(int* __restrict__ partials, int nblk) {
    __shared__ int sh[256];
    int carry = 0;
    for (int base = 0; base < nblk; base += 256) {
        int idx = base + threadIdx.x;
        int v = idx < nblk ? partials[idx] : 0;
        __syncthreads();
        sh[threadIdx.x] = v;
        __syncthreads();
        for (int o = 1; o < 256; o <<= 1) {
            int t = (int)threadIdx.x >= o ? sh[threadIdx.x - o] : 0;
            __syncthreads();
            sh[threadIdx.x] += t;
            __syncthreads();
        }
        int incl = sh[threadIdx.x];
        int total = sh[255];
        if (idx < nblk) partials[idx] = incl - v + carry;
        carry += total;
    }
}

__global__ __launch_bounds__(256) void scan_blocks(const int* __restrict__ counts,
                                                   const int* __restrict__ partials,
                                                   int* __restrict__ offsets,
                                                   int* __restrict__ cursor,
                                                   int CN, int totE) {
    __shared__ int sh[256];
    int gid = blockIdx.x * 256 + threadIdx.x;
    int v = gid < CN ? counts[gid] : 0;
    sh[threadIdx.x] = v;
    __syncthreads();
    for (int o = 1; o < 256; o <<= 1) {
        int t = (int)threadIdx.x >= o ? sh[threadIdx.x - o] : 0;
        __syncthreads();
        sh[threadIdx.x] += t;
        __syncthreads();
    }
    int excl = sh[threadIdx.x] - v + partials[blockIdx.x];
    if (gid < CN) { offsets[gid] = excl; cursor[gid] = excl; }
    if (gid == CN - 1) offsets[CN] = totE;
}

__global__ __launch_bounds__(256) void fill_csr(const int* __restrict__ startn,
                                                const int* __restrict__ endn,
                                                const float* __restrict__ adj,
                                                int* __restrict__ cursor,
                                                int2* __restrict__ payload,
                                                int N, int E, int totE) {
    int tid = blockIdx.x * 256 + threadIdx.x;
    if (tid >= totE) return;
    int i = tid / E;
    int sn = startn[tid];
    int pos = atomicAdd(&cursor[i * N + sn], 1);
    int px = endn[tid] | ((sn & (NT - 1)) << 20);
    payload[pos] = make_int2(px, __builtin_bit_cast(int, adj[tid]));
}

// ---------------- fused aggregate-then-project (round-8 verified, UNCHANGED) --
__global__ __launch_bounds__(512, 4) void fused_agg_gemm(
        const unsigned* __restrict__ xb,          // [N][2][64] dwords (bf16x2)
        const unsigned short* __restrict__ Wfrag, // [7][2048][8]
        const float* __restrict__ bias,           // [7][128]
        const int* __restrict__ offsets,          // [7N+1]
        const int2* __restrict__ payload,         // [7E]
        float* __restrict__ out, int N) {
    __shared__ unsigned ylds[64 * 64];            // 64 rows x 64 dwords, swizzled
    __shared__ float sadjl[ET][NT];
    __shared__ int offs[ET][NT + 1];

    int tid  = threadIdx.x;
    int wave = tid >> 6;
    int lane = tid & 63;
    int hl   = lane & 31;
    int hb   = lane >> 5;          // batch this lane covers
    int lr   = lane & 15;
    int lg   = lane >> 4;
    int rt   = wave & 3;           // row-tile for MFMA
    int ct4  = (wave >> 2) * 4;    // col-tile base for MFMA
    int n0   = blockIdx.x * NT;

    if (tid < ET * (NT + 1)) {
        int i = tid / (NT + 1);
        int j = tid - i * (NT + 1);
        int n = n0 + j;
        ((int*)offs)[tid] = offsets[i * N + (n < N ? n : N)];
    }

    f32x4 acc[4];
#pragma unroll
    for (int c = 0; c < 4; ++c) acc[c] = (f32x4){0.f, 0.f, 0.f, 0.f};

    __syncthreads();

    const unsigned laneoff = (hb << 6) + (hl << 1);
    const int colw = hl << 1;

    for (int i = 0; i < ET; ++i) {
        int base = offs[i][0];
        int tot  = offs[i][NT] - base;
        int tgt_s = base + (int)(((long)tot * wave) >> 3);
        int tgt_e = base + (int)(((long)tot * (wave + 1)) >> 3);
        int oj = (lane <= NT) ? offs[i][lane] : 0x7fffffff;
        unsigned long long ms = __ballot(oj >= tgt_s);
        unsigned long long me = __ballot(oj >= tgt_e);
        int js = __ffsll(ms) - 1;
        int je = (wave == 7) ? NT : (__ffsll(me) - 1);
        int kb = offs[i][js];
        int ke = offs[i][je];

        int cur = -1;
        float a0 = 0.f, a1 = 0.f, a2 = 0.f, a3 = 0.f, asum = 0.f;
        for (int k = kb; k < ke; k += 8) {
            int2 p[8];
            uint2 v[8];
#pragma unroll
            for (int j = 0; j < 8; ++j) {
                int idx = (k + j < ke) ? k + j : ke - 1;
                p[j] = payload[idx];
            }
#pragma unroll
            for (int j = 0; j < 8; ++j) {
                v[j] = *(const uint2*)(xb + (((size_t)(p[j].x & 0xFFFFF)) << 7) + laneoff);
            }
#pragma unroll
            for (int j = 0; j < 8; ++j) {
                bool ok = (k + j) < ke;
                float w = ok ? __builtin_bit_cast(float, p[j].y) : 0.f;
                int nl = (p[j].x >> 20) & (NT - 1);
                if (ok && nl != cur) {
                    if (cur >= 0) {
                        unsigned pk0 = f2bf(a0) | (f2bf(a1) << 16);
                        unsigned pk1 = f2bf(a2) | (f2bf(a3) << 16);
                        int r = hb * NT + cur;
                        *(uint2*)&ylds[(r * 64 + colw) ^ ((r & 7) << 2)] = make_uint2(pk0, pk1);
                        if (lane == 0) sadjl[i][cur] = asum;
                    }
                    cur = nl;
                    a0 = a1 = a2 = a3 = asum = 0.f;
                }
                asum += w;
                a0 += w * lo16(v[j].x); a1 += w * hi16(v[j].x);
                a2 += w * lo16(v[j].y); a3 += w * hi16(v[j].y);
            }
        }
        if (cur >= 0) {
            unsigned pk0 = f2bf(a0) | (f2bf(a1) << 16);
            unsigned pk1 = f2bf(a2) | (f2bf(a3) << 16);
            int r = hb * NT + cur;
            *(uint2*)&ylds[(r * 64 + colw) ^ ((r & 7) << 2)] = make_uint2(pk0, pk1);
            if (lane == 0) sadjl[i][cur] = asum;
        }
        for (int j = js; j < je; ++j) {
            if (offs[i][j + 1] == offs[i][j]) {
                int r = hb * NT + j;
                *(uint2*)&ylds[(r * 64 + colw) ^ ((r & 7) << 2)] = make_uint2(0u, 0u);
                if (lane == 0) sadjl[i][j] = 0.f;
            }
        }
        __syncthreads();

        int row = rt * 16 + lr;
        int s = (row & 7) << 2;
#pragma unroll
        for (int kk = 0; kk < 4; ++kk) {
            int d0 = (row * 64 + kk * 16 + lg * 2) ^ s;
            int d1 = (row * 64 + kk * 16 + lg * 2 + 8) ^ s;
            uint2 c0 = *(const uint2*)&ylds[d0];
            uint2 c1 = *(const uint2*)&ylds[d1];
            uint4v av = {c0.x, c0.y, c1.x, c1.y};
            short8 afrag = __builtin_bit_cast(short8, av);
            const unsigned short* wbp = Wfrag + ((size_t)i * 2048 + (size_t)kk * 64 + lane) * 8;
#pragma unroll
            for (int c = 0; c < 4; ++c) {
                short8 bfrag = *(const short8*)(wbp + (size_t)(ct4 + c) * 2048);
                acc[c] = __builtin_amdgcn_mfma_f32_16x16x32_bf16(afrag, bfrag, acc[c], 0, 0, 0);
            }
        }
        __syncthreads();
    }

#pragma unroll
    for (int c = 0; c < 4; ++c) {
        int col = (ct4 + c) * 16 + lr;
        float bv[ET];
#pragma unroll
        for (int i = 0; i < ET; ++i) bv[i] = bias[i * F + col];
#pragma unroll
        for (int j = 0; j < 4; ++j) {
            int row = rt * 16 + lg * 4 + j;
            int nl = row & (NT - 1);
            int b  = row >> 5;
            int n  = n0 + nl;
            float vv = acc[c][j];
#pragma unroll
            for (int i = 0; i < ET; ++i) vv += sadjl[i][nl] * bv[i];
            if (n < N) out[((size_t)(b * N + n)) * F + col] = vv;
        }
    }
}

// ---------------- fallbacks --------------------------------------------------
__global__ __launch_bounds__(256) void gemm_h(const float* __restrict__ x,
                                              const unsigned short* __restrict__ Wfrag,
                                              const float* __restrict__ bias,
                                              unsigned short* __restrict__ hb,
                                              int M) {
    int wave = threadIdx.x >> 6;
    int lane = threadIdx.x & 63;
    int row_base = blockIdx.x * 128 + wave * 32;
    int lr = lane & 15;
    int lg = lane >> 4;
    f32x4 acc[2][8];
#pragma unroll
    for (int t = 0; t < 2; ++t)
#pragma unroll
        for (int c = 0; c < 8; ++c)
            acc[t][c] = (f32x4){0.f, 0.f, 0.f, 0.f};
#pragma unroll
    for (int kk = 0; kk < 4; ++kk) {
        int k0 = kk * 32 + 4 * lg;
        short8 afrag[2];
#pragma unroll
        for (int t = 0; t < 2; ++t) {
            int r = row_base + t * 16 + lr;
            r = r < M ? r : M - 1;
            float4 v0 = *(const float4*)(x + (size_t)r * F + k0);
            float4 v1 = *(const float4*)(x + (size_t)r * F + k0 + 16);
            short8 a;
            a[0] = (short)f2bf(v0.x); a[1] = (short)f2bf(v0.y);
            a[2] = (short)f2bf(v0.z); a[3] = (short)f2bf(v0.w);
            a[4] = (short)f2bf(v1.x); a[5] = (short)f2bf(v1.y);
            a[6] = (short)f2bf(v1.z); a[7] = (short)f2bf(v1.w);
            afrag[t] = a;
        }
#pragma unroll
        for (int c = 0; c < 8; ++c) {
            short8 bfrag = *(const short8*)(Wfrag + (size_t)((c * 4 + kk) * 64 + lane) * 8);
            acc[0][c] = __builtin_amdgcn_mfma_f32_16x16x32_bf16(afrag[0], bfrag, acc[0][c], 0, 0, 0);
            acc[1][c] = __builtin_amdgcn_mfma_f32_16x16x32_bf16(afrag[1], bfrag, acc[1][c], 0, 0, 0);
        }
    }
#pragma unroll
    for (int c = 0; c < 8; ++c) {
        int o = c * 16 + lr;
        float bvv = bias[o];
#pragma unroll
        for (int t = 0; t < 2; ++t)
#pragma unroll
            for (int j = 0; j < 4; ++j) {
                int r = row_base + t * 16 + lg * 4 + j;
                if (r < M) hb[(size_t)r * F + o] = (unsigned short)f2bf(acc[t][c][j] + bvv);
            }
    }
}

__global__ __launch_bounds__(256) void edge_scatter(const unsigned short* __restrict__ hb,
                                                    const float* __restrict__ adj,
                                                    const int* __restrict__ endn,
                                                    const int* __restrict__ startn,
                                                    float* __restrict__ out,
                                                    int N, int E) {
    int e = blockIdx.x;
    if (e >= E) return;
    int b = threadIdx.x >> 7;
    int f = threadIdx.x & 127;
    float a = adj[e];
    int en = endn[e];
    int sn = startn[e];
    float v = a * bf2f(hb[((size_t)(b * N + en)) * F + f]);
    unsafeAtomicAdd(&out[((size_t)(b * N + sn)) * F + f], v);
}

__global__ __launch_bounds__(256) void edge_fused_slow(const float* __restrict__ x,
                                                       const float* __restrict__ W,
                                                       const float* __restrict__ bias,
                                                       const float* __restrict__ adj,
                                                       const int* __restrict__ endn,
                                                       const int* __restrict__ startn,
                                                       float* __restrict__ out,
                                                       int N, int E) {
    __shared__ float xrow[2][F];
    int e = blockIdx.x;
    if (e >= E) return;
    int b = threadIdx.x >> 7;
    int f = threadIdx.x & 127;
    int en = endn[e], sn = startn[e];
    xrow[b][f] = x[((size_t)(b * N + en)) * F + f];
    __syncthreads();
    float acc = bias[f];
#pragma unroll 8
    for (int k = 0; k < F; ++k) acc += xrow[b][k] * W[k * F + f];
    unsafeAtomicAdd(&out[((size_t)(b * N + sn)) * F + f], adj[e] * acc);
}

// ---------------- launch -----------------------------------------------------
extern "C" void kernel_launch(void* const* d_in, const int* in_sizes, int n_in,
                              void* d_out, int out_size, void* d_ws, size_t ws_size,
                              hipStream_t stream) {
    const float* x      = (const float*)d_in[0];
    const float* W      = (const float*)d_in[1];
    const float* bias   = (const float*)d_in[2];
    const float* adj    = (const float*)d_in[3];
    const int*   endn   = (const int*)d_in[4];
    const int*   startn = (const int*)d_in[5];

    const int B = 2;
    const int N = in_sizes[0] / (B * F);  // 100000
    const int E = in_sizes[3] / ET;       // 400000
    const int M = B * N;                  // 200000
    const int totE = ET * E;              // 2.8M
    const int CN = ET * N;                // 700000
    const int nblk = (CN + 255) / 256;
    const int nbins = (N + BW - 1) >> BSH;
    const int nbt = ET * nbins;
    float* out = (float*)d_out;

    // --- bucket-path ws layout ---
    size_t off = 0;
    auto take = [&](size_t bytes) { size_t o = off; off = (off + bytes + 255) & ~(size_t)255; return o; };
    size_t o_wfrag   = take((size_t)ET * F * F * 2);
    size_t o_bincnt  = take((size_t)nbt * 4);
    size_t o_bases   = take((size_t)(nbt + 1) * 4);
    size_t o_bcur    = take((size_t)nbt * 4);
    size_t o_offsets = take((size_t)(CN + 1) * 4);
    size_t o_tmp     = take((size_t)totE * 8);
    size_t o_payload = take((size_t)totE * 8);
    size_t o_xb      = take((size_t)M * F * 2);
    size_t need_bucket = off;

    // --- old-path ws layout ---
    off = 0;
    size_t q_wfrag    = take((size_t)ET * F * F * 2);
    size_t q_counts   = take((size_t)CN * 4);
    size_t q_offsets  = take((size_t)(CN + 1) * 4);
    size_t q_cursor   = take((size_t)CN * 4);
    size_t q_partials = take((size_t)nblk * 4);
    size_t q_payload  = take((size_t)totE * 8);
    size_t q_xb       = take((size_t)M * F * 2);
    size_t need_old_csr = off;
    size_t need_r1 = 256 * 1024 + (size_t)M * F * 2;

    char* ws = (char*)d_ws;

    if (ws_size >= need_bucket && N < (1 << 17)) {
        unsigned short* Wfrag = (unsigned short*)(ws + o_wfrag);
        int*  bincnt  = (int*)(ws + o_bincnt);
        int*  bases   = (int*)(ws + o_bases);
        int*  bcur    = (int*)(ws + o_bcur);
        int*  offsets = (int*)(ws + o_offsets);
        int2* tmp     = (int2*)(ws + o_tmp);
        int2* payload = (int2*)(ws + o_payload);
        unsigned* xbuf = (unsigned*)(ws + o_xb);

        hipMemsetAsync(bincnt, 0, (size_t)nbt * 4, stream);
        prep_wfrag<<<(ET * 2048 + 255) / 256, 256, 0, stream>>>(W, Wfrag);
        xb_convert<<<2048, 256, 0, stream>>>(x, xbuf, N, (long)M * (F / 2));
        dim3 cg((E + CHUNK - 1) / CHUNK, ET);
        hist_bins2<<<cg, 256, 0, stream>>>(startn, bincnt, E, nbins);
        scan_bins<<<1, 256, 0, stream>>>(bincnt, bases, bcur, nbt, totE, offsets, CN);
        bucket_scatter2<<<cg, 256, 0, stream>>>(startn, endn, adj, bcur, tmp, E, nbins);
        dim3 bg(nbins, ET);
        bin_sort<<<bg, 256, 0, stream>>>(tmp, bases, offsets, payload, N, nbins);

        int fgrid = (N + NT - 1) / NT;
        fused_agg_gemm<<<fgrid, 512, 0, stream>>>(xbuf, Wfrag, bias, offsets, payload, out, N);
    } else if (ws_size >= need_old_csr) {
        unsigned short* Wfrag = (unsigned short*)(ws + q_wfrag);
        int*  counts   = (int*)(ws + q_counts);
        int*  offsets  = (int*)(ws + q_offsets);
        int*  cursor   = (int*)(ws + q_cursor);
        int*  partials = (int*)(ws + q_partials);
        int2* payload  = (int2*)(ws + q_payload);
        unsigned* xbuf = (unsigned*)(ws + q_xb);

        hipMemsetAsync(counts, 0, (size_t)CN * 4, stream);
        prep_wfrag<<<(ET * 2048 + 255) / 256, 256, 0, stream>>>(W, Wfrag);
        xb_convert<<<2048, 256, 0, stream>>>(x, xbuf, N, (long)M * (F / 2));
        hist_kernel<<<(totE + 255) / 256, 256, 0, stream>>>(startn, counts, N, E, totE);
        block_sum<<<nblk, 256, 0, stream>>>(counts, partials, CN);
        scan_partials<<<1, 256, 0, stream>>>(partials, nblk);
        scan_blocks<<<nblk, 256, 0, stream>>>(counts, partials, offsets, cursor, CN, totE);
        fill_csr<<<(totE + 255) / 256, 256, 0, stream>>>(startn, endn, adj, cursor, payload, N, E, totE);

        int fgrid = (N + NT - 1) / NT;
        fused_agg_gemm<<<fgrid, 512, 0, stream>>>(xbuf, Wfrag, bias, offsets, payload, out, N);
    } else if (ws_size >= need_r1) {
        hipMemsetAsync(out, 0, (size_t)out_size * sizeof(float), stream);
        unsigned short* Wfrag = (unsigned short*)d_ws;
        unsigned short* hbuf  = (unsigned short*)((char*)d_ws + 256 * 1024);
        prep_wfrag<<<(ET * 2048 + 255) / 256, 256, 0, stream>>>(W, Wfrag);
        int ggrid = (M + 127) / 128;
        for (int i = 0; i < ET; ++i) {
            gemm_h<<<ggrid, 256, 0, stream>>>(x, Wfrag + (size_t)i * F * F, bias + i * F, hbuf, M);
            edge_scatter<<<E, 256, 0, stream>>>(hbuf, adj + (size_t)i * E, endn + (size_t)i * E,
                                                startn + (size_t)i * E, out, N, E);
        }
    } else {
        hipMemsetAsync(out, 0, (size_t)out_size * sizeof(float), stream);
        for (int i = 0; i < ET; ++i) {
            edge_fused_slow<<<E, 256, 0, stream>>>(x, W + (size_t)i * F * F, bias + i * F,
                                                   adj + (size_t)i * E, endn + (size_t)i * E,
                                                   startn + (size_t)i * E, out, N, E);
        }
    }
}